// Round 8
// baseline (108.699 us; speedup 1.0000x reference)
//
#include <hip/hip_runtime.h>

#define LOSS_EPS 0.001f
#define EPS_PAR 1e-12f
#define EPS_PT 1e-12f

typedef float f32x4 __attribute__((ext_vector_type(4)));
typedef int   i32x4 __attribute__((ext_vector_type(4)));

__device__ __forceinline__ f32x4 vmin4(f32x4 a, f32x4 b) { return __builtin_elementwise_min(a, b); }
__device__ __forceinline__ f32x4 vmax4(f32x4 a, f32x4 b) { return __builtin_elementwise_max(a, b); }
__device__ __forceinline__ f32x4 vclamp01(f32x4 v) {
    return vmin4(vmax4(v, (f32x4)0.0f), (f32x4)1.0f);
}
__device__ __forceinline__ f32x4 vrcp(f32x4 x) {
    f32x4 r;
    r.x = __builtin_amdgcn_rcpf(x.x); r.y = __builtin_amdgcn_rcpf(x.y);
    r.z = __builtin_amdgcn_rcpf(x.z); r.w = __builtin_amdgcn_rcpf(x.w);
    return r;
}
__device__ __forceinline__ f32x4 vsel(i32x4 m, f32x4 a, f32x4 b) {
    i32x4 ai = __builtin_bit_cast(i32x4, a);
    i32x4 bi = __builtin_bit_cast(i32x4, b);
    i32x4 r = (ai & m) | (bi & ~m);
    return __builtin_bit_cast(f32x4, r);
}

struct V3q { f32x4 x, y, z; };
__device__ __forceinline__ V3q operator-(V3q a, V3q b) { return {a.x - b.x, a.y - b.y, a.z - b.z}; }
__device__ __forceinline__ V3q operator+(V3q a, V3q b) { return {a.x + b.x, a.y + b.y, a.z + b.z}; }
__device__ __forceinline__ V3q operator*(f32x4 s, V3q a) { return {s * a.x, s * a.y, s * a.z}; }
__device__ __forceinline__ f32x4 dotq(V3q a, V3q b) { return a.x * b.x + a.y * b.y + a.z * b.z; }

__device__ __forceinline__ f32x4 edge_edge_d2(V3q p1, V3q d1, V3q p2, V3q d2,
                                              f32x4 a, f32x4 e, f32x4 ra, f32x4 re) {
    V3q r = p1 - p2;
    f32x4 f = dotq(d2, r);
    f32x4 b = dotq(d1, d2);
    f32x4 c = dotq(d1, r);
    f32x4 denom = a * e - b * b;
    i32x4 par = denom < (f32x4)EPS_PAR;
    f32x4 rd = vrcp(vsel(par, (f32x4)1.0f, denom));
    f32x4 s = (b * f - c * e) * rd;
    f32x4 t = (a * f - b * c) * rd;
    s = vsel(par, (f32x4)0.0f, s);
    f32x4 s_cl = vclamp01(s);
    f32x4 t_cl = vclamp01(t);
    i32x4 rec_t = (s_cl != s) | par;
    V3q r_new = r + s_cl * d1;
    f32x4 t_new = vclamp01(dotq(r_new, d2) * re);
    f32x4 t_fin = vsel(rec_t, t_new, t_cl);
    i32x4 rec_s = (t_cl != t) & ~par & (s_cl == s);
    V3q r_new2 = r - t_fin * d2;
    f32x4 s_new = (-dotq(r_new2, d1)) * ra;
    f32x4 s_fin = vsel(rec_s, vclamp01(s_new), s_cl);
    V3q c1 = p1 + s_fin * d1;
    V3q c2 = p2 + t_fin * d2;
    V3q diff = c1 - c2;
    return dotq(diff, diff);
}

__device__ __forceinline__ f32x4 ptri3_min_d2(V3q p0, V3q p1, V3q p2,
                                              V3q v0, V3q v1, V3q v2) {
    V3q e0 = v1 - v0;
    V3q e1 = v2 - v0;
    V3q e2t = v2 - v1;
    f32x4 a  = vmax4(dotq(e0, e0), (f32x4)EPS_PT);
    f32x4 b  = dotq(e0, e1);
    f32x4 c  = vmax4(dotq(e1, e1), (f32x4)EPS_PT);
    f32x4 a2 = vmax4(dotq(e2t, e2t), (f32x4)EPS_PT);
    f32x4 det = vmax4(a * c - b * b, (f32x4)EPS_PT);
    f32x4 ra = vrcp(a), rc = vrcp(c), ra2 = vrcp(a2), rdet = vrcp(det);

    f32x4 best = (f32x4)1e30f;
    V3q pts[3] = {p0, p1, p2};
#pragma unroll
    for (int k = 0; k < 3; ++k) {
        V3q p = pts[k];
        V3q w = p - v0;
        f32x4 d = dotq(e0, w);
        f32x4 e = dotq(e1, w);
        f32x4 f = dotq(w, w);
        f32x4 s = b * e - c * d;
        f32x4 t = b * d - a * e;
        i32x4 in_face = (s >= (f32x4)0.0f) & (t >= (f32x4)0.0f) & ((s + t) <= det);
        f32x4 s01 = vclamp01(d * ra);
        V3q u01 = w - s01 * e0;
        f32x4 d2_e01 = dotq(u01, u01);
        f32x4 t02 = vclamp01(e * rc);
        V3q u02 = w - t02 * e1;
        f32x4 d2_e02 = dotq(u02, u02);
        V3q w2 = p - v1;
        f32x4 dd2 = dotq(e2t, w2);
        f32x4 u12 = vclamp01(dd2 * ra2);
        V3q u12v = w2 - u12 * e2t;
        f32x4 d2_e12 = dotq(u12v, u12v);
        f32x4 d2_face = vmax4((f * det - (d * s + e * t)) * rdet, (f32x4)0.0f);
        f32x4 d2_edge = vmin4(vmin4(d2_e01, d2_e02), d2_e12);
        best = vmin4(best, vsel(in_face, d2_face, d2_edge));
    }
    return best;
}

// Quad-packed body: component c = pair c of this body.
__device__ __forceinline__ f32x4 body_from_T(const f32x4 T1[9], const f32x4 T2[9], f32x4 vmask) {
    V3q A[3]  = { {T1[0], T1[1], T1[2]}, {T1[3], T1[4], T1[5]}, {T1[6], T1[7], T1[8]} };
    V3q Ac[3] = { {T1[0], T1[3], T1[6]}, {T1[1], T1[4], T1[7]}, {T1[2], T1[5], T1[8]} };
    V3q B[3]  = { {T2[0], T2[1], T2[2]}, {T2[3], T2[4], T2[5]}, {T2[6], T2[7], T2[8]} };
    V3q Bc[3] = { {T2[0], T2[3], T2[6]}, {T2[1], T2[4], T2[7]}, {T2[2], T2[5], T2[8]} };

    f32x4 mind2 = (f32x4)1e30f;
    mind2 = vmin4(mind2, ptri3_min_d2(A[0], A[1], A[2], Bc[0], Bc[1], Bc[2]));
    mind2 = vmin4(mind2, ptri3_min_d2(B[0], B[1], B[2], Ac[0], Ac[1], Ac[2]));

    V3q dA[3] = { A[1] - A[0], A[2] - A[1], A[0] - A[2] };
    V3q dB[3] = { B[1] - B[0], B[2] - B[1], B[0] - B[2] };
    f32x4 la[3], lb[3], rla[3], rlb[3];
#pragma unroll
    for (int k = 0; k < 3; ++k) {
        la[k] = dotq(dA[k], dA[k]); rla[k] = vrcp(la[k]);
        lb[k] = dotq(dB[k], dB[k]); rlb[k] = vrcp(lb[k]);
    }
#pragma unroll
    for (int ii = 0; ii < 3; ++ii) {
#pragma unroll
        for (int jj = 0; jj < 3; ++jj) {
            mind2 = vmin4(mind2, edge_edge_d2(A[ii], dA[ii], B[jj], dB[jj],
                                              la[ii], lb[jj], rla[ii], rlb[jj]));
        }
    }
    f32x4 dist;
    dist.x = __builtin_sqrtf(mind2.x);
    dist.y = __builtin_sqrtf(mind2.y);
    dist.z = __builtin_sqrtf(mind2.z);
    dist.w = __builtin_sqrtf(mind2.w);
    return vmax4((f32x4)LOSS_EPS - dist, (f32x4)0.0f) * vmask;
}

__device__ __forceinline__ void block_reduce_atomic(float pen, float val, float* ws) {
#pragma unroll
    for (int off = 32; off > 0; off >>= 1) {
        pen += __shfl_down(pen, off);
        val += __shfl_down(val, off);
    }
    __shared__ float sp[4], sv[4];
    int wid = threadIdx.x >> 6;
    if ((threadIdx.x & 63) == 0) { sp[wid] = pen; sv[wid] = val; }
    __syncthreads();
    if (threadIdx.x == 0) {
        atomicAdd(&ws[0], sp[0] + sp[1] + sp[2] + sp[3]);
        atomicAdd(&ws[1], sv[0] + sv[1] + sv[2] + sv[3]);
    }
}

// Repack 9-float (36B) triangles into 64B-aligned 16-float slots.
// Also zeroes the accumulators (saves a memset dispatch).
__global__ void __launch_bounds__(256)
prep_kernel(const float* __restrict__ tris, float4* __restrict__ pack,
            float* __restrict__ ws, int ntri) {
    int g = blockIdx.x * 256 + threadIdx.x;
    if (g == 0) { ws[0] = 0.0f; ws[1] = 0.0f; }
    if (g >= ntri) return;
    const float* s = tris + (size_t)g * 9;
    float t[9];
#pragma unroll
    for (int k = 0; k < 9; ++k) t[k] = s[k];
    float4* d = pack + (size_t)g * 4;
    d[0] = make_float4(t[0], t[1], t[2], t[3]);
    d[1] = make_float4(t[4], t[5], t[6], t[7]);
    d[2] = make_float4(t[8], 0.0f, 0.0f, 0.0f);
}

#define PPT 8                         // pairs per thread: 2 quad-packed bodies
#define PAIRS_PER_BLOCK (256 * PPT)   // 2048

__global__ void __launch_bounds__(256)
pen_loss_pipe4(const float* __restrict__ packf, const int* __restrict__ idx,
               float* __restrict__ ws, int npairs, int F, int P, int nwg) {
    // Bijective XCD chunk swizzle (m204).
    int pb = blockIdx.x;
    int x = pb & 7, j = pb >> 3;
    int q8 = nwg >> 3, r8 = nwg & 7;
    int start = (x < r8) ? x * (q8 + 1) : r8 * (q8 + 1) + (x - r8) * q8;
    int lb = start + j;
    int tid = (int)threadIdx.x;
    int p0 = lb * PAIRS_PER_BLOCK + tid;

    // 1) All idx loads upfront (coalesced, nontemporal: keep L2 for the table).
    int o1[PPT], o2[PPT];
    float vm[PPT];
#pragma unroll
    for (int k = 0; k < PPT; ++k) {
        int p = p0 + k * 256;
        int pc = min(p, npairs - 1);
        long long pr = __builtin_nontemporal_load((const long long*)idx + pc);
        int rx = (int)(pr & 0xffffffffLL);
        int ry = (int)(pr >> 32);
        vm[k] = (p < npairs && rx >= 0) ? 1.0f : 0.0f;
        int b = (pc >= P) + (pc >= 2 * P) + (pc >= 3 * P);   // pc / P without idiv
        int base = b * F;
        o1[k] = (base + max(rx, 0)) * 16;   // float offsets into 16-float slots
        o2[k] = (base + max(ry, 0)) * 16;
    }

    // Staging for one quad-body (4 pairs): 9 floats per triangle (2 quads + 1 scalar).
    float4 qA0[4], qA1[4], qB0[4], qB1[4];
    float  qA2[4], qB2[4];

#define LOADBODY(m) do {                                                       \
        _Pragma("unroll")                                                      \
        for (int c = 0; c < 4; ++c) {                                          \
            const int pi = 4 * (m) + c;                                        \
            qA0[c] = *(const float4*)(packf + o1[pi]);                         \
            qA1[c] = *(const float4*)(packf + o1[pi] + 4);                     \
            qA2[c] = packf[o1[pi] + 8];                                        \
            qB0[c] = *(const float4*)(packf + o2[pi]);                         \
            qB1[c] = *(const float4*)(packf + o2[pi] + 4);                     \
            qB2[c] = packf[o2[pi] + 8];                                        \
        }                                                                      \
    } while (0)

#define PACKT(T1, T2) do {                                                     \
        T1[0] = (f32x4){qA0[0].x, qA0[1].x, qA0[2].x, qA0[3].x};               \
        T1[1] = (f32x4){qA0[0].y, qA0[1].y, qA0[2].y, qA0[3].y};               \
        T1[2] = (f32x4){qA0[0].z, qA0[1].z, qA0[2].z, qA0[3].z};               \
        T1[3] = (f32x4){qA0[0].w, qA0[1].w, qA0[2].w, qA0[3].w};               \
        T1[4] = (f32x4){qA1[0].x, qA1[1].x, qA1[2].x, qA1[3].x};               \
        T1[5] = (f32x4){qA1[0].y, qA1[1].y, qA1[2].y, qA1[3].y};               \
        T1[6] = (f32x4){qA1[0].z, qA1[1].z, qA1[2].z, qA1[3].z};               \
        T1[7] = (f32x4){qA1[0].w, qA1[1].w, qA1[2].w, qA1[3].w};               \
        T1[8] = (f32x4){qA2[0], qA2[1], qA2[2], qA2[3]};                       \
        T2[0] = (f32x4){qB0[0].x, qB0[1].x, qB0[2].x, qB0[3].x};               \
        T2[1] = (f32x4){qB0[0].y, qB0[1].y, qB0[2].y, qB0[3].y};               \
        T2[2] = (f32x4){qB0[0].z, qB0[1].z, qB0[2].z, qB0[3].z};               \
        T2[3] = (f32x4){qB0[0].w, qB0[1].w, qB0[2].w, qB0[3].w};               \
        T2[4] = (f32x4){qB1[0].x, qB1[1].x, qB1[2].x, qB1[3].x};               \
        T2[5] = (f32x4){qB1[0].y, qB1[1].y, qB1[2].y, qB1[3].y};               \
        T2[6] = (f32x4){qB1[0].z, qB1[1].z, qB1[2].z, qB1[3].z};               \
        T2[7] = (f32x4){qB1[0].w, qB1[1].w, qB1[2].w, qB1[3].w};               \
        T2[8] = (f32x4){qB2[0], qB2[1], qB2[2], qB2[3]};                       \
    } while (0)

    LOADBODY(0);
    f32x4 pen4 = (f32x4)0.0f;
    {
        f32x4 T1[9], T2[9];
        PACKT(T1, T2);           // consumes staging (waits loads), frees it
        LOADBODY(1);             // body-1 gathers fly under body-0 compute
        f32x4 vm4 = {vm[0], vm[1], vm[2], vm[3]};
        pen4 += body_from_T(T1, T2, vm4);
    }
    {
        f32x4 T1[9], T2[9];
        PACKT(T1, T2);
        f32x4 vm4 = {vm[4], vm[5], vm[6], vm[7]};
        pen4 += body_from_T(T1, T2, vm4);
    }
#undef LOADBODY
#undef PACKT

    float pen_s = pen4.x + pen4.y + pen4.z + pen4.w;
    float val_s = 0.0f;
#pragma unroll
    for (int k = 0; k < PPT; ++k) val_s += vm[k];
    block_reduce_atomic(pen_s, val_s, ws);
}

// -------- scalar fallback (workspace too small) --------
struct V3 { float x, y, z; };
__device__ __forceinline__ V3 operator-(V3 a, V3 b) { return {a.x - b.x, a.y - b.y, a.z - b.z}; }
__device__ __forceinline__ V3 operator+(V3 a, V3 b) { return {a.x + b.x, a.y + b.y, a.z + b.z}; }
__device__ __forceinline__ V3 operator*(float s, V3 a) { return {s * a.x, s * a.y, s * a.z}; }
__device__ __forceinline__ float dot(V3 a, V3 b) { return a.x * b.x + a.y * b.y + a.z * b.z; }
__device__ __forceinline__ float clamp01(float v) { return fminf(fmaxf(v, 0.0f), 1.0f); }
__device__ __forceinline__ float frcp(float x) { return __builtin_amdgcn_rcpf(x); }

__device__ float pair_body_scalar(const float t1[9], const float t2[9], float val) {
    V3 A[3]  = { {t1[0], t1[1], t1[2]}, {t1[3], t1[4], t1[5]}, {t1[6], t1[7], t1[8]} };
    V3 Ac[3] = { {t1[0], t1[3], t1[6]}, {t1[1], t1[4], t1[7]}, {t1[2], t1[5], t1[8]} };
    V3 B[3]  = { {t2[0], t2[1], t2[2]}, {t2[3], t2[4], t2[5]}, {t2[6], t2[7], t2[8]} };
    V3 Bc[3] = { {t2[0], t2[3], t2[6]}, {t2[1], t2[4], t2[7]}, {t2[2], t2[5], t2[8]} };
    float mind2 = 1e30f;
#pragma unroll
    for (int dir = 0; dir < 2; ++dir) {
        V3* P3 = dir ? B : A;
        V3* T3 = dir ? Ac : Bc;
        V3 e0 = T3[1] - T3[0], e1 = T3[2] - T3[0], e2t = T3[2] - T3[1];
        float a = fmaxf(dot(e0, e0), EPS_PT), b = dot(e0, e1);
        float c = fmaxf(dot(e1, e1), EPS_PT), a2 = fmaxf(dot(e2t, e2t), EPS_PT);
        float det = fmaxf(a * c - b * b, EPS_PT);
        float ra = frcp(a), rc = frcp(c), ra2 = frcp(a2), rdet = frcp(det);
#pragma unroll
        for (int k = 0; k < 3; ++k) {
            V3 p = P3[k];
            V3 w = p - T3[0];
            float d = dot(e0, w), e = dot(e1, w), f = dot(w, w);
            float s = b * e - c * d, t = b * d - a * e;
            bool in_face = (s >= 0.0f) && (t >= 0.0f) && (s + t <= det);
            float s01 = clamp01(d * ra);
            V3 u01 = w - s01 * e0;
            float t02 = clamp01(e * rc);
            V3 u02 = w - t02 * e1;
            V3 w2 = p - T3[1];
            float u12 = clamp01(dot(e2t, w2) * ra2);
            V3 u12v = w2 - u12 * e2t;
            float d2_face = fmaxf((f * det - (d * s + e * t)) * rdet, 0.0f);
            float d2_edge = fminf(fminf(dot(u01, u01), dot(u02, u02)), dot(u12v, u12v));
            mind2 = fminf(mind2, in_face ? d2_face : d2_edge);
        }
    }
    V3 dA[3] = { A[1] - A[0], A[2] - A[1], A[0] - A[2] };
    V3 dB[3] = { B[1] - B[0], B[2] - B[1], B[0] - B[2] };
#pragma unroll
    for (int ii = 0; ii < 3; ++ii) {
#pragma unroll
        for (int jj = 0; jj < 3; ++jj) {
            V3 d1 = dA[ii], d2 = dB[jj];
            V3 r = A[ii] - B[jj];
            float a = dot(d1, d1), e = dot(d2, d2);
            float f = dot(d2, r), b = dot(d1, d2), c = dot(d1, r);
            float denom = a * e - b * b;
            bool par = denom < EPS_PAR;
            float rd = frcp(par ? 1.0f : denom);
            float s = (b * f - c * e) * rd;
            float t = (a * f - b * c) * rd;
            s = par ? 0.0f : s;
            float s_cl = clamp01(s), t_cl = clamp01(t);
            bool rec_t = (s_cl != s) || par;
            V3 rn = r + s_cl * d1;
            float t_new = clamp01(dot(rn, d2) * frcp(e));
            float t_fin = rec_t ? t_new : t_cl;
            bool rec_s = (t_cl != t) && (!par) && (s_cl == s);
            V3 rn2 = r - t_fin * d2;
            float s_new = (-dot(rn2, d1)) * frcp(a);
            float s_fin = rec_s ? clamp01(s_new) : s_cl;
            V3 diff = (A[ii] + s_fin * d1) - (B[jj] + t_fin * d2);
            mind2 = fminf(mind2, dot(diff, diff));
        }
    }
    return fmaxf(LOSS_EPS - sqrtf(mind2), 0.0f) * val;
}

__global__ void __launch_bounds__(256)
pen_loss_direct(const float* __restrict__ tris, const int2* __restrict__ idx,
                float* __restrict__ ws, int npairs, int F, int P) {
    int i = blockIdx.x * 256 + threadIdx.x;
    float pen = 0.0f, val = 0.0f;
    if (i < npairs) {
        int b = i / P;
        int2 ij = idx[i];
        val = (ij.x >= 0) ? 1.0f : 0.0f;
        const float* T1 = tris + ((size_t)b * (size_t)F + (size_t)max(ij.x, 0)) * 9;
        const float* T2 = tris + ((size_t)b * (size_t)F + (size_t)max(ij.y, 0)) * 9;
        float t1[9], t2[9];
#pragma unroll
        for (int k = 0; k < 9; ++k) t1[k] = T1[k];
#pragma unroll
        for (int k = 0; k < 9; ++k) t2[k] = T2[k];
        pen = pair_body_scalar(t1, t2, val);
    }
    block_reduce_atomic(pen, val, ws);
}

__global__ void finalize_kernel(const float* __restrict__ ws, float* __restrict__ out) {
    out[0] = ws[0] / fmaxf(ws[1], 1.0f);
}

extern "C" void kernel_launch(void* const* d_in, const int* in_sizes, int n_in,
                              void* d_out, int out_size, void* d_ws, size_t ws_size,
                              hipStream_t stream) {
    const float* tris = (const float*)d_in[0];
    const int* idx = (const int*)d_in[1];
    float* out = (float*)d_out;
    float* ws = (float*)d_ws;

    const int B = 4;
    int F = in_sizes[0] / (B * 9);      // 50000
    int npairs = in_sizes[1] / 2;       // 2,000,000
    int P = npairs / B;                 // 500,000
    int ntri = B * F;                   // 200,000

    size_t need = 256 + (size_t)ntri * 64;
    if (ws_size >= need) {
        float* packf = (float*)((char*)d_ws + 256);
        prep_kernel<<<(ntri + 255) / 256, 256, 0, stream>>>(tris, (float4*)packf, ws, ntri);
        int nwg = (npairs + PAIRS_PER_BLOCK - 1) / PAIRS_PER_BLOCK;   // 977
        pen_loss_pipe4<<<nwg, 256, 0, stream>>>(packf, idx, ws,
                                                npairs, F, P, nwg);
    } else {
        hipMemsetAsync(d_ws, 0, 2 * sizeof(float), stream);
        int nwg = (npairs + 255) / 256;
        pen_loss_direct<<<nwg, 256, 0, stream>>>(tris, (const int2*)idx, ws,
                                                 npairs, F, P);
    }
    finalize_kernel<<<1, 1, 0, stream>>>(ws, out);
}

// Round 9
// 90.777 us; speedup vs baseline: 1.1974x; 1.1974x over previous
//
#include <hip/hip_runtime.h>

#define LOSS_EPS 0.001f
#define EPS_PAR 1e-12f
#define EPS_PT 1e-12f

typedef float f32x2 __attribute__((ext_vector_type(2)));
typedef int   i32x2 __attribute__((ext_vector_type(2)));

__device__ __forceinline__ f32x2 vmin2(f32x2 a, f32x2 b) { return __builtin_elementwise_min(a, b); }
__device__ __forceinline__ f32x2 vmax2(f32x2 a, f32x2 b) { return __builtin_elementwise_max(a, b); }
__device__ __forceinline__ f32x2 vclamp01(f32x2 v) {
    return vmin2(vmax2(v, (f32x2)0.0f), (f32x2)1.0f);
}
__device__ __forceinline__ f32x2 vrcp(f32x2 x) {
    f32x2 r; r.x = __builtin_amdgcn_rcpf(x.x); r.y = __builtin_amdgcn_rcpf(x.y); return r;
}
// Per-component select; sext(cmp)!=0 folds back to the compare -> v_cndmask.
__device__ __forceinline__ f32x2 vsel(i32x2 m, f32x2 a, f32x2 b) {
    f32x2 r;
    r.x = m.x ? a.x : b.x;
    r.y = m.y ? a.y : b.y;
    return r;
}

struct V3p { f32x2 x, y, z; };
__device__ __forceinline__ V3p operator-(V3p a, V3p b) { return {a.x - b.x, a.y - b.y, a.z - b.z}; }
__device__ __forceinline__ V3p operator+(V3p a, V3p b) { return {a.x + b.x, a.y + b.y, a.z + b.z}; }
__device__ __forceinline__ V3p operator*(f32x2 s, V3p a) { return {s * a.x, s * a.y, s * a.z}; }
__device__ __forceinline__ f32x2 dotp(V3p a, V3p b) { return a.x * b.x + a.y * b.y + a.z * b.z; }

__device__ __forceinline__ f32x2 edge_edge_d2(V3p p1, V3p d1, V3p p2, V3p d2,
                                              f32x2 a, f32x2 e, f32x2 ra, f32x2 re) {
    V3p r = p1 - p2;
    f32x2 f = dotp(d2, r);
    f32x2 b = dotp(d1, d2);
    f32x2 c = dotp(d1, r);
    f32x2 denom = a * e - b * b;
    i32x2 par = denom < (f32x2)EPS_PAR;
    f32x2 rd = vrcp(vsel(par, (f32x2)1.0f, denom));
    f32x2 s = (b * f - c * e) * rd;
    f32x2 t = (a * f - b * c) * rd;
    s = vsel(par, (f32x2)0.0f, s);
    f32x2 s_cl = vclamp01(s);
    f32x2 t_cl = vclamp01(t);
    i32x2 rec_t = (s_cl != s) | par;
    V3p r_new = r + s_cl * d1;
    f32x2 t_new = vclamp01(dotp(r_new, d2) * re);
    f32x2 t_fin = vsel(rec_t, t_new, t_cl);
    i32x2 rec_s = (t_cl != t) & ~par & (s_cl == s);
    V3p r_new2 = r - t_fin * d2;
    f32x2 s_new = (-dotp(r_new2, d1)) * ra;
    f32x2 s_fin = vsel(rec_s, vclamp01(s_new), s_cl);
    V3p c1 = p1 + s_fin * d1;
    V3p c2 = p2 + t_fin * d2;
    V3p diff = c1 - c2;
    return dotp(diff, diff);
}

__device__ __forceinline__ f32x2 ptri3_min_d2(V3p p0, V3p p1, V3p p2,
                                              V3p v0, V3p v1, V3p v2) {
    V3p e0 = v1 - v0;
    V3p e1 = v2 - v0;
    V3p e2t = v2 - v1;
    f32x2 a  = vmax2(dotp(e0, e0), (f32x2)EPS_PT);
    f32x2 b  = dotp(e0, e1);
    f32x2 c  = vmax2(dotp(e1, e1), (f32x2)EPS_PT);
    f32x2 a2 = vmax2(dotp(e2t, e2t), (f32x2)EPS_PT);
    f32x2 det = vmax2(a * c - b * b, (f32x2)EPS_PT);
    f32x2 ra = vrcp(a), rc = vrcp(c), ra2 = vrcp(a2), rdet = vrcp(det);

    f32x2 best = (f32x2)1e30f;
    V3p pts[3] = {p0, p1, p2};
#pragma unroll
    for (int k = 0; k < 3; ++k) {
        V3p p = pts[k];
        V3p w = p - v0;
        f32x2 d = dotp(e0, w);
        f32x2 e = dotp(e1, w);
        f32x2 f = dotp(w, w);
        f32x2 s = b * e - c * d;
        f32x2 t = b * d - a * e;
        i32x2 in_face = (s >= (f32x2)0.0f) & (t >= (f32x2)0.0f) & ((s + t) <= det);
        f32x2 s01 = vclamp01(d * ra);
        V3p u01 = w - s01 * e0;
        f32x2 d2_e01 = dotp(u01, u01);
        f32x2 t02 = vclamp01(e * rc);
        V3p u02 = w - t02 * e1;
        f32x2 d2_e02 = dotp(u02, u02);
        V3p w2 = p - v1;
        f32x2 dd2 = dotp(e2t, w2);
        f32x2 u12 = vclamp01(dd2 * ra2);
        V3p u12v = w2 - u12 * e2t;
        f32x2 d2_e12 = dotp(u12v, u12v);
        f32x2 d2_face = vmax2((f * det - (d * s + e * t)) * rdet, (f32x2)0.0f);
        f32x2 d2_edge = vmin2(vmin2(d2_e01, d2_e02), d2_e12);
        best = vmin2(best, vsel(in_face, d2_face, d2_edge));
    }
    return best;
}

// Packed body operating on pre-transposed T arrays (component 0 = even pair, 1 = odd pair).
__device__ __forceinline__ f32x2 body_from_T(const f32x2 T1[9], const f32x2 T2[9], f32x2 vmask) {
    V3p A[3]  = { {T1[0], T1[1], T1[2]}, {T1[3], T1[4], T1[5]}, {T1[6], T1[7], T1[8]} };
    V3p Ac[3] = { {T1[0], T1[3], T1[6]}, {T1[1], T1[4], T1[7]}, {T1[2], T1[5], T1[8]} };
    V3p B[3]  = { {T2[0], T2[1], T2[2]}, {T2[3], T2[4], T2[5]}, {T2[6], T2[7], T2[8]} };
    V3p Bc[3] = { {T2[0], T2[3], T2[6]}, {T2[1], T2[4], T2[7]}, {T2[2], T2[5], T2[8]} };

    f32x2 mind2 = (f32x2)1e30f;
    mind2 = vmin2(mind2, ptri3_min_d2(A[0], A[1], A[2], Bc[0], Bc[1], Bc[2]));
    mind2 = vmin2(mind2, ptri3_min_d2(B[0], B[1], B[2], Ac[0], Ac[1], Ac[2]));

    V3p dA[3] = { A[1] - A[0], A[2] - A[1], A[0] - A[2] };
    V3p dB[3] = { B[1] - B[0], B[2] - B[1], B[0] - B[2] };
    f32x2 la[3], lb[3], rla[3], rlb[3];
#pragma unroll
    for (int k = 0; k < 3; ++k) {
        la[k] = dotp(dA[k], dA[k]); rla[k] = vrcp(la[k]);
        lb[k] = dotp(dB[k], dB[k]); rlb[k] = vrcp(lb[k]);
    }
#pragma unroll
    for (int ii = 0; ii < 3; ++ii) {
#pragma unroll
        for (int jj = 0; jj < 3; ++jj) {
            mind2 = vmin2(mind2, edge_edge_d2(A[ii], dA[ii], B[jj], dB[jj],
                                              la[ii], lb[jj], rla[ii], rlb[jj]));
        }
    }
    f32x2 dist;
    dist.x = __builtin_sqrtf(mind2.x);
    dist.y = __builtin_sqrtf(mind2.y);
    return vmax2((f32x2)LOSS_EPS - dist, (f32x2)0.0f) * vmask;
}

// Block reduce + global accumulate; the LAST block to finish also writes the final loss.
__device__ __forceinline__ void block_reduce_atomic_fused(float pen, float val, float* ws,
                                                          float* out, unsigned nwg) {
#pragma unroll
    for (int off = 32; off > 0; off >>= 1) {
        pen += __shfl_down(pen, off);
        val += __shfl_down(val, off);
    }
    __shared__ float sp[4], sv[4];
    int wid = threadIdx.x >> 6;
    if ((threadIdx.x & 63) == 0) { sp[wid] = pen; sv[wid] = val; }
    __syncthreads();
    if (threadIdx.x == 0) {
        atomicAdd(&ws[0], sp[0] + sp[1] + sp[2] + sp[3]);
        atomicAdd(&ws[1], sv[0] + sv[1] + sv[2] + sv[3]);
        __threadfence();                              // publish sums before counter
        unsigned done = atomicAdd((unsigned*)(ws + 2), 1u);
        if (done == nwg - 1) {                        // last block: finalize
            float p = atomicAdd(&ws[0], 0.0f);        // atomic read (device scope)
            float v = atomicAdd(&ws[1], 0.0f);
            out[0] = p / fmaxf(v, 1.0f);
        }
    }
}

// Repack 9-float (36B) triangles into 64B-aligned slots; zero the 3 accumulators.
__global__ void __launch_bounds__(256)
prep_kernel(const float* __restrict__ tris, float4* __restrict__ pack,
            float* __restrict__ ws, int ntri) {
    int g = blockIdx.x * 256 + threadIdx.x;
    if (g == 0) { ws[0] = 0.0f; ws[1] = 0.0f; ((unsigned*)ws)[2] = 0u; }
    if (g >= ntri) return;
    const float* s = tris + (size_t)g * 9;
    float t[9];
#pragma unroll
    for (int k = 0; k < 9; ++k) t[k] = s[k];
    float4* d = pack + (size_t)g * 4;
    d[0] = make_float4(t[0], t[1], t[2], t[3]);
    d[1] = make_float4(t[4], t[5], t[6], t[7]);
    d[2] = make_float4(t[8], 0.0f, 0.0f, 0.0f);
}

#define PPT 8                         // pairs per thread (4 packed bodies)
#define PAIRS_PER_BLOCK (256 * PPT)   // 2048

__global__ void __launch_bounds__(256)
pen_loss_pipe2(const float4* __restrict__ pack, const int* __restrict__ idx,
               float* __restrict__ ws, float* __restrict__ out,
               int npairs, int F, int P, int nwg) {
    // Bijective XCD chunk swizzle (m204).
    int pb = blockIdx.x;
    int x = pb & 7, j = pb >> 3;
    int q8 = nwg >> 3, r8 = nwg & 7;
    int start = (x < r8) ? x * (q8 + 1) : r8 * (q8 + 1) + (x - r8) * q8;
    int lb = start + j;
    int tid = (int)threadIdx.x;
    int p0 = lb * PAIRS_PER_BLOCK + tid;

    // 1) All idx loads upfront (coalesced, nontemporal: keep L2 for the table).
    int o1[PPT], o2[PPT];
    float vm[PPT];
#pragma unroll
    for (int k = 0; k < PPT; ++k) {
        int p = p0 + k * 256;
        int pc = min(p, npairs - 1);
        long long pr = __builtin_nontemporal_load((const long long*)idx + pc);
        int rx = (int)(pr & 0xffffffffLL);
        int ry = (int)(pr >> 32);
        vm[k] = (p < npairs && rx >= 0) ? 1.0f : 0.0f;
        int b = (pc >= P) + (pc >= 2 * P) + (pc >= 3 * P);   // pc / P without idiv
        int base = b * F;
        o1[k] = (base + max(rx, 0)) * 4;
        o2[k] = (base + max(ry, 0)) * 4;
    }

    // Single 12-quad buffer: transpose frees it, then next body's loads refill it
    // while the ~1400-cycle packed body runs. All indices static.
    float4 qb_[12];

#define LOADBODY(m) do {                                                      \
        const int ev = 2 * (m), od = 2 * (m) + 1;                             \
        qb_[0] = pack[o1[ev]];     qb_[1] = pack[o1[ev] + 1];                 \
        qb_[2] = pack[o1[ev] + 2]; qb_[3] = pack[o2[ev]];                     \
        qb_[4] = pack[o2[ev] + 1]; qb_[5] = pack[o2[ev] + 2];                 \
        qb_[6] = pack[o1[od]];     qb_[7] = pack[o1[od] + 1];                 \
        qb_[8] = pack[o1[od] + 2]; qb_[9] = pack[o2[od]];                     \
        qb_[10] = pack[o2[od] + 1]; qb_[11] = pack[o2[od] + 2];               \
    } while (0)

#define PACKT(T1, T2) do {                                                    \
        T1[0] = (f32x2){qb_[0].x, qb_[6].x}; T1[1] = (f32x2){qb_[0].y, qb_[6].y}; \
        T1[2] = (f32x2){qb_[0].z, qb_[6].z}; T1[3] = (f32x2){qb_[0].w, qb_[6].w}; \
        T1[4] = (f32x2){qb_[1].x, qb_[7].x}; T1[5] = (f32x2){qb_[1].y, qb_[7].y}; \
        T1[6] = (f32x2){qb_[1].z, qb_[7].z}; T1[7] = (f32x2){qb_[1].w, qb_[7].w}; \
        T1[8] = (f32x2){qb_[2].x, qb_[8].x};                                      \
        T2[0] = (f32x2){qb_[3].x, qb_[9].x}; T2[1] = (f32x2){qb_[3].y, qb_[9].y}; \
        T2[2] = (f32x2){qb_[3].z, qb_[9].z}; T2[3] = (f32x2){qb_[3].w, qb_[9].w}; \
        T2[4] = (f32x2){qb_[4].x, qb_[10].x}; T2[5] = (f32x2){qb_[4].y, qb_[10].y}; \
        T2[6] = (f32x2){qb_[4].z, qb_[10].z}; T2[7] = (f32x2){qb_[4].w, qb_[10].w}; \
        T2[8] = (f32x2){qb_[5].x, qb_[11].x};                                     \
    } while (0)

    LOADBODY(0);
    f32x2 pen2 = (f32x2)0.0f;
#pragma unroll
    for (int m = 0; m < PPT / 2; ++m) {
        f32x2 T1[9], T2[9];
        PACKT(T1, T2);                     // consumes qb_ (waits loads), frees it
        if (m < PPT / 2 - 1) LOADBODY(m + 1);  // next body's gathers fly under the body
        f32x2 vmm = {vm[2 * m], vm[2 * m + 1]};
        pen2 += body_from_T(T1, T2, vmm);
    }
#undef LOADBODY
#undef PACKT

    float pen_s = pen2.x + pen2.y;
    float val_s = 0.0f;
#pragma unroll
    for (int k = 0; k < PPT; ++k) val_s += vm[k];
    block_reduce_atomic_fused(pen_s, val_s, ws, out, (unsigned)nwg);
}

// -------- scalar fallback (workspace too small) --------
struct V3 { float x, y, z; };
__device__ __forceinline__ V3 operator-(V3 a, V3 b) { return {a.x - b.x, a.y - b.y, a.z - b.z}; }
__device__ __forceinline__ V3 operator+(V3 a, V3 b) { return {a.x + b.x, a.y + b.y, a.z + b.z}; }
__device__ __forceinline__ V3 operator*(float s, V3 a) { return {s * a.x, s * a.y, s * a.z}; }
__device__ __forceinline__ float dot(V3 a, V3 b) { return a.x * b.x + a.y * b.y + a.z * b.z; }
__device__ __forceinline__ float clamp01(float v) { return fminf(fmaxf(v, 0.0f), 1.0f); }
__device__ __forceinline__ float frcp(float x) { return __builtin_amdgcn_rcpf(x); }

__device__ float pair_body_scalar(const float t1[9], const float t2[9], float val) {
    V3 A[3]  = { {t1[0], t1[1], t1[2]}, {t1[3], t1[4], t1[5]}, {t1[6], t1[7], t1[8]} };
    V3 Ac[3] = { {t1[0], t1[3], t1[6]}, {t1[1], t1[4], t1[7]}, {t1[2], t1[5], t1[8]} };
    V3 B[3]  = { {t2[0], t2[1], t2[2]}, {t2[3], t2[4], t2[5]}, {t2[6], t2[7], t2[8]} };
    V3 Bc[3] = { {t2[0], t2[3], t2[6]}, {t2[1], t2[4], t2[7]}, {t2[2], t2[5], t2[8]} };
    float mind2 = 1e30f;
#pragma unroll
    for (int dir = 0; dir < 2; ++dir) {
        V3* P3 = dir ? B : A;
        V3* T3 = dir ? Ac : Bc;
        V3 e0 = T3[1] - T3[0], e1 = T3[2] - T3[0], e2t = T3[2] - T3[1];
        float a = fmaxf(dot(e0, e0), EPS_PT), b = dot(e0, e1);
        float c = fmaxf(dot(e1, e1), EPS_PT), a2 = fmaxf(dot(e2t, e2t), EPS_PT);
        float det = fmaxf(a * c - b * b, EPS_PT);
        float ra = frcp(a), rc = frcp(c), ra2 = frcp(a2), rdet = frcp(det);
#pragma unroll
        for (int k = 0; k < 3; ++k) {
            V3 p = P3[k];
            V3 w = p - T3[0];
            float d = dot(e0, w), e = dot(e1, w), f = dot(w, w);
            float s = b * e - c * d, t = b * d - a * e;
            bool in_face = (s >= 0.0f) && (t >= 0.0f) && (s + t <= det);
            float s01 = clamp01(d * ra);
            V3 u01 = w - s01 * e0;
            float t02 = clamp01(e * rc);
            V3 u02 = w - t02 * e1;
            V3 w2 = p - T3[1];
            float u12 = clamp01(dot(e2t, w2) * ra2);
            V3 u12v = w2 - u12 * e2t;
            float d2_face = fmaxf((f * det - (d * s + e * t)) * rdet, 0.0f);
            float d2_edge = fminf(fminf(dot(u01, u01), dot(u02, u02)), dot(u12v, u12v));
            mind2 = fminf(mind2, in_face ? d2_face : d2_edge);
        }
    }
    V3 dA[3] = { A[1] - A[0], A[2] - A[1], A[0] - A[2] };
    V3 dB[3] = { B[1] - B[0], B[2] - B[1], B[0] - B[2] };
#pragma unroll
    for (int ii = 0; ii < 3; ++ii) {
#pragma unroll
        for (int jj = 0; jj < 3; ++jj) {
            V3 d1 = dA[ii], d2 = dB[jj];
            V3 r = A[ii] - B[jj];
            float a = dot(d1, d1), e = dot(d2, d2);
            float f = dot(d2, r), b = dot(d1, d2), c = dot(d1, r);
            float denom = a * e - b * b;
            bool par = denom < EPS_PAR;
            float rd = frcp(par ? 1.0f : denom);
            float s = (b * f - c * e) * rd;
            float t = (a * f - b * c) * rd;
            s = par ? 0.0f : s;
            float s_cl = clamp01(s), t_cl = clamp01(t);
            bool rec_t = (s_cl != s) || par;
            V3 rn = r + s_cl * d1;
            float t_new = clamp01(dot(rn, d2) * frcp(e));
            float t_fin = rec_t ? t_new : t_cl;
            bool rec_s = (t_cl != t) && (!par) && (s_cl == s);
            V3 rn2 = r - t_fin * d2;
            float s_new = (-dot(rn2, d1)) * frcp(a);
            float s_fin = rec_s ? clamp01(s_new) : s_cl;
            V3 diff = (A[ii] + s_fin * d1) - (B[jj] + t_fin * d2);
            mind2 = fminf(mind2, dot(diff, diff));
        }
    }
    return fmaxf(LOSS_EPS - sqrtf(mind2), 0.0f) * val;
}

__device__ __forceinline__ void block_reduce_atomic(float pen, float val, float* ws) {
#pragma unroll
    for (int off = 32; off > 0; off >>= 1) {
        pen += __shfl_down(pen, off);
        val += __shfl_down(val, off);
    }
    __shared__ float sp[4], sv[4];
    int wid = threadIdx.x >> 6;
    if ((threadIdx.x & 63) == 0) { sp[wid] = pen; sv[wid] = val; }
    __syncthreads();
    if (threadIdx.x == 0) {
        atomicAdd(&ws[0], sp[0] + sp[1] + sp[2] + sp[3]);
        atomicAdd(&ws[1], sv[0] + sv[1] + sv[2] + sv[3]);
    }
}

__global__ void __launch_bounds__(256)
pen_loss_direct(const float* __restrict__ tris, const int2* __restrict__ idx,
                float* __restrict__ ws, int npairs, int F, int P) {
    int i = blockIdx.x * 256 + threadIdx.x;
    float pen = 0.0f, val = 0.0f;
    if (i < npairs) {
        int b = i / P;
        int2 ij = idx[i];
        val = (ij.x >= 0) ? 1.0f : 0.0f;
        const float* T1 = tris + ((size_t)b * (size_t)F + (size_t)max(ij.x, 0)) * 9;
        const float* T2 = tris + ((size_t)b * (size_t)F + (size_t)max(ij.y, 0)) * 9;
        float t1[9], t2[9];
#pragma unroll
        for (int k = 0; k < 9; ++k) t1[k] = T1[k];
#pragma unroll
        for (int k = 0; k < 9; ++k) t2[k] = T2[k];
        pen = pair_body_scalar(t1, t2, val);
    }
    block_reduce_atomic(pen, val, ws);
}

__global__ void finalize_kernel(const float* __restrict__ ws, float* __restrict__ out) {
    out[0] = ws[0] / fmaxf(ws[1], 1.0f);
}

extern "C" void kernel_launch(void* const* d_in, const int* in_sizes, int n_in,
                              void* d_out, int out_size, void* d_ws, size_t ws_size,
                              hipStream_t stream) {
    const float* tris = (const float*)d_in[0];
    const int* idx = (const int*)d_in[1];
    float* out = (float*)d_out;
    float* ws = (float*)d_ws;

    const int B = 4;
    int F = in_sizes[0] / (B * 9);      // 50000
    int npairs = in_sizes[1] / 2;       // 2,000,000
    int P = npairs / B;                 // 500,000
    int ntri = B * F;                   // 200,000

    size_t need = 256 + (size_t)ntri * 64;
    if (ws_size >= need) {
        float4* pack = (float4*)((char*)d_ws + 256);
        prep_kernel<<<(ntri + 255) / 256, 256, 0, stream>>>(tris, pack, ws, ntri);
        int nwg = (npairs + PAIRS_PER_BLOCK - 1) / PAIRS_PER_BLOCK;   // 977
        pen_loss_pipe2<<<nwg, 256, 0, stream>>>(pack, idx, ws, out,
                                                npairs, F, P, nwg);
        // finalize fused into the last block of pen_loss_pipe2
    } else {
        hipMemsetAsync(d_ws, 0, 2 * sizeof(float), stream);
        int nwg = (npairs + 255) / 256;
        pen_loss_direct<<<nwg, 256, 0, stream>>>(tris, (const int2*)idx, ws,
                                                 npairs, F, P);
        finalize_kernel<<<1, 1, 0, stream>>>(ws, out);
    }
}

// Round 10
// 79.444 us; speedup vs baseline: 1.3682x; 1.1426x over previous
//
#include <hip/hip_runtime.h>

#define LOSS_EPS 0.001f
#define EPS_PAR 1e-12f
#define EPS_PT 1e-12f

typedef float f32x2 __attribute__((ext_vector_type(2)));
typedef int   i32x2 __attribute__((ext_vector_type(2)));

__device__ __forceinline__ f32x2 vmin2(f32x2 a, f32x2 b) { return __builtin_elementwise_min(a, b); }
__device__ __forceinline__ f32x2 vmax2(f32x2 a, f32x2 b) { return __builtin_elementwise_max(a, b); }
__device__ __forceinline__ f32x2 vclamp01(f32x2 v) {
    return vmin2(vmax2(v, (f32x2)0.0f), (f32x2)1.0f);
}
__device__ __forceinline__ f32x2 vrcp(f32x2 x) {
    f32x2 r; r.x = __builtin_amdgcn_rcpf(x.x); r.y = __builtin_amdgcn_rcpf(x.y); return r;
}
// bit-select: m ? a : b per component (R6-proven form; do NOT use ternaries — R9 regression)
__device__ __forceinline__ f32x2 vsel(i32x2 m, f32x2 a, f32x2 b) {
    i32x2 ai = __builtin_bit_cast(i32x2, a);
    i32x2 bi = __builtin_bit_cast(i32x2, b);
    i32x2 r = (ai & m) | (bi & ~m);
    return __builtin_bit_cast(f32x2, r);
}

struct V3p { f32x2 x, y, z; };
__device__ __forceinline__ V3p operator-(V3p a, V3p b) { return {a.x - b.x, a.y - b.y, a.z - b.z}; }
__device__ __forceinline__ V3p operator+(V3p a, V3p b) { return {a.x + b.x, a.y + b.y, a.z + b.z}; }
__device__ __forceinline__ V3p operator*(f32x2 s, V3p a) { return {s * a.x, s * a.y, s * a.z}; }
__device__ __forceinline__ f32x2 dotp(V3p a, V3p b) { return a.x * b.x + a.y * b.y + a.z * b.z; }

__device__ __forceinline__ f32x2 edge_edge_d2(V3p p1, V3p d1, V3p p2, V3p d2,
                                              f32x2 a, f32x2 e, f32x2 ra, f32x2 re) {
    V3p r = p1 - p2;
    f32x2 f = dotp(d2, r);
    f32x2 b = dotp(d1, d2);
    f32x2 c = dotp(d1, r);
    f32x2 denom = a * e - b * b;
    i32x2 par = denom < (f32x2)EPS_PAR;
    f32x2 rd = vrcp(vsel(par, (f32x2)1.0f, denom));
    f32x2 s = (b * f - c * e) * rd;
    f32x2 t = (a * f - b * c) * rd;
    s = vsel(par, (f32x2)0.0f, s);
    f32x2 s_cl = vclamp01(s);
    f32x2 t_cl = vclamp01(t);
    i32x2 rec_t = (s_cl != s) | par;
    V3p r_new = r + s_cl * d1;
    f32x2 t_new = vclamp01(dotp(r_new, d2) * re);
    f32x2 t_fin = vsel(rec_t, t_new, t_cl);
    i32x2 rec_s = (t_cl != t) & ~par & (s_cl == s);
    V3p r_new2 = r - t_fin * d2;
    f32x2 s_new = (-dotp(r_new2, d1)) * ra;
    f32x2 s_fin = vsel(rec_s, vclamp01(s_new), s_cl);
    V3p c1 = p1 + s_fin * d1;
    V3p c2 = p2 + t_fin * d2;
    V3p diff = c1 - c2;
    return dotp(diff, diff);
}

__device__ __forceinline__ f32x2 ptri3_min_d2(V3p p0, V3p p1, V3p p2,
                                              V3p v0, V3p v1, V3p v2) {
    V3p e0 = v1 - v0;
    V3p e1 = v2 - v0;
    V3p e2t = v2 - v1;
    f32x2 a  = vmax2(dotp(e0, e0), (f32x2)EPS_PT);
    f32x2 b  = dotp(e0, e1);
    f32x2 c  = vmax2(dotp(e1, e1), (f32x2)EPS_PT);
    f32x2 a2 = vmax2(dotp(e2t, e2t), (f32x2)EPS_PT);
    f32x2 det = vmax2(a * c - b * b, (f32x2)EPS_PT);
    f32x2 ra = vrcp(a), rc = vrcp(c), ra2 = vrcp(a2), rdet = vrcp(det);

    f32x2 best = (f32x2)1e30f;
    V3p pts[3] = {p0, p1, p2};
#pragma unroll
    for (int k = 0; k < 3; ++k) {
        V3p p = pts[k];
        V3p w = p - v0;
        f32x2 d = dotp(e0, w);
        f32x2 e = dotp(e1, w);
        f32x2 f = dotp(w, w);
        f32x2 s = b * e - c * d;
        f32x2 t = b * d - a * e;
        i32x2 in_face = (s >= (f32x2)0.0f) & (t >= (f32x2)0.0f) & ((s + t) <= det);
        f32x2 s01 = vclamp01(d * ra);
        V3p u01 = w - s01 * e0;
        f32x2 d2_e01 = dotp(u01, u01);
        f32x2 t02 = vclamp01(e * rc);
        V3p u02 = w - t02 * e1;
        f32x2 d2_e02 = dotp(u02, u02);
        V3p w2 = p - v1;
        f32x2 dd2 = dotp(e2t, w2);
        f32x2 u12 = vclamp01(dd2 * ra2);
        V3p u12v = w2 - u12 * e2t;
        f32x2 d2_e12 = dotp(u12v, u12v);
        f32x2 d2_face = vmax2((f * det - (d * s + e * t)) * rdet, (f32x2)0.0f);
        f32x2 d2_edge = vmin2(vmin2(d2_e01, d2_e02), d2_e12);
        best = vmin2(best, vsel(in_face, d2_face, d2_edge));
    }
    return best;
}

// Packed body operating on pre-transposed T arrays (component 0 = even pair, 1 = odd pair).
__device__ __forceinline__ f32x2 body_from_T(const f32x2 T1[9], const f32x2 T2[9], f32x2 vmask) {
    V3p A[3]  = { {T1[0], T1[1], T1[2]}, {T1[3], T1[4], T1[5]}, {T1[6], T1[7], T1[8]} };
    V3p Ac[3] = { {T1[0], T1[3], T1[6]}, {T1[1], T1[4], T1[7]}, {T1[2], T1[5], T1[8]} };
    V3p B[3]  = { {T2[0], T2[1], T2[2]}, {T2[3], T2[4], T2[5]}, {T2[6], T2[7], T2[8]} };
    V3p Bc[3] = { {T2[0], T2[3], T2[6]}, {T2[1], T2[4], T2[7]}, {T2[2], T2[5], T2[8]} };

    f32x2 mind2 = (f32x2)1e30f;
    mind2 = vmin2(mind2, ptri3_min_d2(A[0], A[1], A[2], Bc[0], Bc[1], Bc[2]));
    mind2 = vmin2(mind2, ptri3_min_d2(B[0], B[1], B[2], Ac[0], Ac[1], Ac[2]));

    V3p dA[3] = { A[1] - A[0], A[2] - A[1], A[0] - A[2] };
    V3p dB[3] = { B[1] - B[0], B[2] - B[1], B[0] - B[2] };
    f32x2 la[3], lb[3], rla[3], rlb[3];
#pragma unroll
    for (int k = 0; k < 3; ++k) {
        la[k] = dotp(dA[k], dA[k]); rla[k] = vrcp(la[k]);
        lb[k] = dotp(dB[k], dB[k]); rlb[k] = vrcp(lb[k]);
    }
#pragma unroll
    for (int ii = 0; ii < 3; ++ii) {
#pragma unroll
        for (int jj = 0; jj < 3; ++jj) {
            mind2 = vmin2(mind2, edge_edge_d2(A[ii], dA[ii], B[jj], dB[jj],
                                              la[ii], lb[jj], rla[ii], rlb[jj]));
        }
    }
    f32x2 dist;
    dist.x = __builtin_sqrtf(mind2.x);
    dist.y = __builtin_sqrtf(mind2.y);
    return vmax2((f32x2)LOSS_EPS - dist, (f32x2)0.0f) * vmask;
}

// Block reduce + global accumulate; the LAST block to finish also writes the final loss.
__device__ __forceinline__ void block_reduce_atomic_fused(float pen, float val, float* ws,
                                                          float* out, unsigned nwg) {
#pragma unroll
    for (int off = 32; off > 0; off >>= 1) {
        pen += __shfl_down(pen, off);
        val += __shfl_down(val, off);
    }
    __shared__ float sp[4], sv[4];
    int wid = threadIdx.x >> 6;
    if ((threadIdx.x & 63) == 0) { sp[wid] = pen; sv[wid] = val; }
    __syncthreads();
    if (threadIdx.x == 0) {
        atomicAdd(&ws[0], sp[0] + sp[1] + sp[2] + sp[3]);
        atomicAdd(&ws[1], sv[0] + sv[1] + sv[2] + sv[3]);
        __threadfence();                              // publish sums before counter
        unsigned done = atomicAdd((unsigned*)(ws + 2), 1u);
        if (done == nwg - 1) {                        // last block: finalize
            float p = atomicAdd(&ws[0], 0.0f);        // device-scope atomic read
            float v = atomicAdd(&ws[1], 0.0f);
            out[0] = p / fmaxf(v, 1.0f);
        }
    }
}

// Repack 9-float (36B) triangles into 64B-aligned slots; zero the 3 accumulators.
__global__ void __launch_bounds__(256)
prep_kernel(const float* __restrict__ tris, float4* __restrict__ pack,
            float* __restrict__ ws, int ntri) {
    int g = blockIdx.x * 256 + threadIdx.x;
    if (g == 0) { ws[0] = 0.0f; ws[1] = 0.0f; ((unsigned*)ws)[2] = 0u; }
    if (g >= ntri) return;
    const float* s = tris + (size_t)g * 9;
    float t[9];
#pragma unroll
    for (int k = 0; k < 9; ++k) t[k] = s[k];
    float4* d = pack + (size_t)g * 4;
    d[0] = make_float4(t[0], t[1], t[2], t[3]);
    d[1] = make_float4(t[4], t[5], t[6], t[7]);
    d[2] = make_float4(t[8], 0.0f, 0.0f, 0.0f);
}

#define PPT 16                        // pairs per thread (8 packed bodies)
#define PAIRS_PER_BLOCK (256 * PPT)   // 4096

__global__ void __launch_bounds__(256)
pen_loss_pipe2(const float4* __restrict__ pack, const int* __restrict__ idx,
               float* __restrict__ ws, float* __restrict__ out,
               int npairs, int F, int P, int nwg) {
    // Bijective XCD chunk swizzle (m204).
    int pb = blockIdx.x;
    int x = pb & 7, j = pb >> 3;
    int q8 = nwg >> 3, r8 = nwg & 7;
    int start = (x < r8) ? x * (q8 + 1) : r8 * (q8 + 1) + (x - r8) * q8;
    int lb = start + j;
    int tid = (int)threadIdx.x;
    int p0 = lb * PAIRS_PER_BLOCK + tid;

    // 1) All 16 raw idx loads in flight upfront (coalesced, nontemporal).
    //    Only the raw 8B words are kept live (32 VGPR); offsets/masks are
    //    recomputed per body (cheap ALU) to stay under the 128-VGPR cliff.
    long long praw[PPT];
#pragma unroll
    for (int k = 0; k < PPT; ++k) {
        int pc = min(p0 + k * 256, npairs - 1);
        praw[k] = __builtin_nontemporal_load((const long long*)idx + pc);
    }

    // Single 12-quad staging buffer: PACKT consumes it, next LOADBODY refills it
    // while the ~3500-cycle packed body runs. All indices static.
    float4 qb_[12];

#define OFFS(k, oAv, oBv)                                                     \
        int pc_ = min(p0 + (k) * 256, npairs - 1);                            \
        int rx_ = (int)(praw[k] & 0xffffffffLL);                              \
        int ry_ = (int)(praw[k] >> 32);                                       \
        int b_ = (pc_ >= P) + (pc_ >= 2 * P) + (pc_ >= 3 * P);                \
        int oAv = (b_ * F + max(rx_, 0)) * 4;                                 \
        int oBv = (b_ * F + max(ry_, 0)) * 4;

#define LOADBODY(m) do {                                                      \
        { OFFS(2 * (m), oA, oB)                                               \
          qb_[0] = pack[oA]; qb_[1] = pack[oA + 1]; qb_[2] = pack[oA + 2];    \
          qb_[3] = pack[oB]; qb_[4] = pack[oB + 1]; qb_[5] = pack[oB + 2]; }  \
        { OFFS(2 * (m) + 1, oA, oB)                                           \
          qb_[6] = pack[oA]; qb_[7] = pack[oA + 1]; qb_[8] = pack[oA + 2];    \
          qb_[9] = pack[oB]; qb_[10] = pack[oB + 1]; qb_[11] = pack[oB + 2]; }\
    } while (0)

#define PACKT(T1, T2) do {                                                    \
        T1[0] = (f32x2){qb_[0].x, qb_[6].x}; T1[1] = (f32x2){qb_[0].y, qb_[6].y}; \
        T1[2] = (f32x2){qb_[0].z, qb_[6].z}; T1[3] = (f32x2){qb_[0].w, qb_[6].w}; \
        T1[4] = (f32x2){qb_[1].x, qb_[7].x}; T1[5] = (f32x2){qb_[1].y, qb_[7].y}; \
        T1[6] = (f32x2){qb_[1].z, qb_[7].z}; T1[7] = (f32x2){qb_[1].w, qb_[7].w}; \
        T1[8] = (f32x2){qb_[2].x, qb_[8].x};                                      \
        T2[0] = (f32x2){qb_[3].x, qb_[9].x}; T2[1] = (f32x2){qb_[3].y, qb_[9].y}; \
        T2[2] = (f32x2){qb_[3].z, qb_[9].z}; T2[3] = (f32x2){qb_[3].w, qb_[9].w}; \
        T2[4] = (f32x2){qb_[4].x, qb_[10].x}; T2[5] = (f32x2){qb_[4].y, qb_[10].y}; \
        T2[6] = (f32x2){qb_[4].z, qb_[10].z}; T2[7] = (f32x2){qb_[4].w, qb_[10].w}; \
        T2[8] = (f32x2){qb_[5].x, qb_[11].x};                                     \
    } while (0)

    LOADBODY(0);
    f32x2 pen2 = (f32x2)0.0f;
    float val_s = 0.0f;
#pragma unroll
    for (int m = 0; m < PPT / 2; ++m) {
        f32x2 T1[9], T2[9];
        PACKT(T1, T2);                     // consumes qb_ (waits loads), frees it
        if (m < PPT / 2 - 1) LOADBODY(m + 1);  // next body's gathers fly under the body
        // validity masks recomputed from raw idx (no persistent vm[] array)
        int pe = p0 + (2 * m) * 256;
        int po = p0 + (2 * m + 1) * 256;
        float vme = (pe < npairs && (int)(praw[2 * m] & 0xffffffffLL) >= 0) ? 1.0f : 0.0f;
        float vmo = (po < npairs && (int)(praw[2 * m + 1] & 0xffffffffLL) >= 0) ? 1.0f : 0.0f;
        f32x2 vmm = {vme, vmo};
        pen2 += body_from_T(T1, T2, vmm);
        val_s += vme + vmo;
    }
#undef LOADBODY
#undef PACKT
#undef OFFS

    float pen_s = pen2.x + pen2.y;
    block_reduce_atomic_fused(pen_s, val_s, ws, out, (unsigned)nwg);
}

// -------- scalar fallback (workspace too small) --------
struct V3 { float x, y, z; };
__device__ __forceinline__ V3 operator-(V3 a, V3 b) { return {a.x - b.x, a.y - b.y, a.z - b.z}; }
__device__ __forceinline__ V3 operator+(V3 a, V3 b) { return {a.x + b.x, a.y + b.y, a.z + b.z}; }
__device__ __forceinline__ V3 operator*(float s, V3 a) { return {s * a.x, s * a.y, s * a.z}; }
__device__ __forceinline__ float dot(V3 a, V3 b) { return a.x * b.x + a.y * b.y + a.z * b.z; }
__device__ __forceinline__ float clamp01(float v) { return fminf(fmaxf(v, 0.0f), 1.0f); }
__device__ __forceinline__ float frcp(float x) { return __builtin_amdgcn_rcpf(x); }

__device__ float pair_body_scalar(const float t1[9], const float t2[9], float val) {
    V3 A[3]  = { {t1[0], t1[1], t1[2]}, {t1[3], t1[4], t1[5]}, {t1[6], t1[7], t1[8]} };
    V3 Ac[3] = { {t1[0], t1[3], t1[6]}, {t1[1], t1[4], t1[7]}, {t1[2], t1[5], t1[8]} };
    V3 B[3]  = { {t2[0], t2[1], t2[2]}, {t2[3], t2[4], t2[5]}, {t2[6], t2[7], t2[8]} };
    V3 Bc[3] = { {t2[0], t2[3], t2[6]}, {t2[1], t2[4], t2[7]}, {t2[2], t2[5], t2[8]} };
    float mind2 = 1e30f;
#pragma unroll
    for (int dir = 0; dir < 2; ++dir) {
        V3* P3 = dir ? B : A;
        V3* T3 = dir ? Ac : Bc;
        V3 e0 = T3[1] - T3[0], e1 = T3[2] - T3[0], e2t = T3[2] - T3[1];
        float a = fmaxf(dot(e0, e0), EPS_PT), b = dot(e0, e1);
        float c = fmaxf(dot(e1, e1), EPS_PT), a2 = fmaxf(dot(e2t, e2t), EPS_PT);
        float det = fmaxf(a * c - b * b, EPS_PT);
        float ra = frcp(a), rc = frcp(c), ra2 = frcp(a2), rdet = frcp(det);
#pragma unroll
        for (int k = 0; k < 3; ++k) {
            V3 p = P3[k];
            V3 w = p - T3[0];
            float d = dot(e0, w), e = dot(e1, w), f = dot(w, w);
            float s = b * e - c * d, t = b * d - a * e;
            bool in_face = (s >= 0.0f) && (t >= 0.0f) && (s + t <= det);
            float s01 = clamp01(d * ra);
            V3 u01 = w - s01 * e0;
            float t02 = clamp01(e * rc);
            V3 u02 = w - t02 * e1;
            V3 w2 = p - T3[1];
            float u12 = clamp01(dot(e2t, w2) * ra2);
            V3 u12v = w2 - u12 * e2t;
            float d2_face = fmaxf((f * det - (d * s + e * t)) * rdet, 0.0f);
            float d2_edge = fminf(fminf(dot(u01, u01), dot(u02, u02)), dot(u12v, u12v));
            mind2 = fminf(mind2, in_face ? d2_face : d2_edge);
        }
    }
    V3 dA[3] = { A[1] - A[0], A[2] - A[1], A[0] - A[2] };
    V3 dB[3] = { B[1] - B[0], B[2] - B[1], B[0] - B[2] };
#pragma unroll
    for (int ii = 0; ii < 3; ++ii) {
#pragma unroll
        for (int jj = 0; jj < 3; ++jj) {
            V3 d1 = dA[ii], d2 = dB[jj];
            V3 r = A[ii] - B[jj];
            float a = dot(d1, d1), e = dot(d2, d2);
            float f = dot(d2, r), b = dot(d1, d2), c = dot(d1, r);
            float denom = a * e - b * b;
            bool par = denom < EPS_PAR;
            float rd = frcp(par ? 1.0f : denom);
            float s = (b * f - c * e) * rd;
            float t = (a * f - b * c) * rd;
            s = par ? 0.0f : s;
            float s_cl = clamp01(s), t_cl = clamp01(t);
            bool rec_t = (s_cl != s) || par;
            V3 rn = r + s_cl * d1;
            float t_new = clamp01(dot(rn, d2) * frcp(e));
            float t_fin = rec_t ? t_new : t_cl;
            bool rec_s = (t_cl != t) && (!par) && (s_cl == s);
            V3 rn2 = r - t_fin * d2;
            float s_new = (-dot(rn2, d1)) * frcp(a);
            float s_fin = rec_s ? clamp01(s_new) : s_cl;
            V3 diff = (A[ii] + s_fin * d1) - (B[jj] + t_fin * d2);
            mind2 = fminf(mind2, dot(diff, diff));
        }
    }
    return fmaxf(LOSS_EPS - sqrtf(mind2), 0.0f) * val;
}

__device__ __forceinline__ void block_reduce_atomic(float pen, float val, float* ws) {
#pragma unroll
    for (int off = 32; off > 0; off >>= 1) {
        pen += __shfl_down(pen, off);
        val += __shfl_down(val, off);
    }
    __shared__ float sp[4], sv[4];
    int wid = threadIdx.x >> 6;
    if ((threadIdx.x & 63) == 0) { sp[wid] = pen; sv[wid] = val; }
    __syncthreads();
    if (threadIdx.x == 0) {
        atomicAdd(&ws[0], sp[0] + sp[1] + sp[2] + sp[3]);
        atomicAdd(&ws[1], sv[0] + sv[1] + sv[2] + sv[3]);
    }
}

__global__ void __launch_bounds__(256)
pen_loss_direct(const float* __restrict__ tris, const int2* __restrict__ idx,
                float* __restrict__ ws, int npairs, int F, int P) {
    int i = blockIdx.x * 256 + threadIdx.x;
    float pen = 0.0f, val = 0.0f;
    if (i < npairs) {
        int b = i / P;
        int2 ij = idx[i];
        val = (ij.x >= 0) ? 1.0f : 0.0f;
        const float* T1 = tris + ((size_t)b * (size_t)F + (size_t)max(ij.x, 0)) * 9;
        const float* T2 = tris + ((size_t)b * (size_t)F + (size_t)max(ij.y, 0)) * 9;
        float t1[9], t2[9];
#pragma unroll
        for (int k = 0; k < 9; ++k) t1[k] = T1[k];
#pragma unroll
        for (int k = 0; k < 9; ++k) t2[k] = T2[k];
        pen = pair_body_scalar(t1, t2, val);
    }
    block_reduce_atomic(pen, val, ws);
}

__global__ void finalize_kernel(const float* __restrict__ ws, float* __restrict__ out) {
    out[0] = ws[0] / fmaxf(ws[1], 1.0f);
}

extern "C" void kernel_launch(void* const* d_in, const int* in_sizes, int n_in,
                              void* d_out, int out_size, void* d_ws, size_t ws_size,
                              hipStream_t stream) {
    const float* tris = (const float*)d_in[0];
    const int* idx = (const int*)d_in[1];
    float* out = (float*)d_out;
    float* ws = (float*)d_ws;

    const int B = 4;
    int F = in_sizes[0] / (B * 9);      // 50000
    int npairs = in_sizes[1] / 2;       // 2,000,000
    int P = npairs / B;                 // 500,000
    int ntri = B * F;                   // 200,000

    size_t need = 256 + (size_t)ntri * 64;
    if (ws_size >= need) {
        float4* pack = (float4*)((char*)d_ws + 256);
        prep_kernel<<<(ntri + 255) / 256, 256, 0, stream>>>(tris, pack, ws, ntri);
        int nwg = (npairs + PAIRS_PER_BLOCK - 1) / PAIRS_PER_BLOCK;   // 489
        pen_loss_pipe2<<<nwg, 256, 0, stream>>>(pack, idx, ws, out,
                                                npairs, F, P, nwg);
        // finalize fused into the last block of pen_loss_pipe2
    } else {
        hipMemsetAsync(d_ws, 0, 2 * sizeof(float), stream);
        int nwg = (npairs + 255) / 256;
        pen_loss_direct<<<nwg, 256, 0, stream>>>(tris, (const int2*)idx, ws,
                                                 npairs, F, P);
        finalize_kernel<<<1, 1, 0, stream>>>(ws, out);
    }
}

// Round 11
// 75.598 us; speedup vs baseline: 1.4379x; 1.0509x over previous
//
#include <hip/hip_runtime.h>

#define LOSS_EPS 0.001f
#define EPS_PAR 1e-12f
#define EPS_PT 1e-12f

typedef float f32x2 __attribute__((ext_vector_type(2)));
typedef int   i32x2 __attribute__((ext_vector_type(2)));

__device__ __forceinline__ f32x2 vmin2(f32x2 a, f32x2 b) { return __builtin_elementwise_min(a, b); }
__device__ __forceinline__ f32x2 vmax2(f32x2 a, f32x2 b) { return __builtin_elementwise_max(a, b); }
__device__ __forceinline__ f32x2 vclamp01(f32x2 v) {
    return vmin2(vmax2(v, (f32x2)0.0f), (f32x2)1.0f);
}
__device__ __forceinline__ f32x2 vrcp(f32x2 x) {
    f32x2 r; r.x = __builtin_amdgcn_rcpf(x.x); r.y = __builtin_amdgcn_rcpf(x.y); return r;
}
// bit-select: m ? a : b per component (R6-proven form; ternaries regressed in R9)
__device__ __forceinline__ f32x2 vsel(i32x2 m, f32x2 a, f32x2 b) {
    i32x2 ai = __builtin_bit_cast(i32x2, a);
    i32x2 bi = __builtin_bit_cast(i32x2, b);
    i32x2 r = (ai & m) | (bi & ~m);
    return __builtin_bit_cast(f32x2, r);
}

struct V3p { f32x2 x, y, z; };
__device__ __forceinline__ V3p operator-(V3p a, V3p b) { return {a.x - b.x, a.y - b.y, a.z - b.z}; }
__device__ __forceinline__ V3p operator+(V3p a, V3p b) { return {a.x + b.x, a.y + b.y, a.z + b.z}; }
__device__ __forceinline__ V3p operator*(f32x2 s, V3p a) { return {s * a.x, s * a.y, s * a.z}; }
__device__ __forceinline__ f32x2 dotp(V3p a, V3p b) { return a.x * b.x + a.y * b.y + a.z * b.z; }

__device__ __forceinline__ f32x2 edge_edge_d2(V3p p1, V3p d1, V3p p2, V3p d2,
                                              f32x2 a, f32x2 e, f32x2 ra, f32x2 re) {
    V3p r = p1 - p2;
    f32x2 f = dotp(d2, r);
    f32x2 b = dotp(d1, d2);
    f32x2 c = dotp(d1, r);
    f32x2 denom = a * e - b * b;
    i32x2 par = denom < (f32x2)EPS_PAR;
    f32x2 rd = vrcp(vsel(par, (f32x2)1.0f, denom));
    f32x2 s = (b * f - c * e) * rd;
    f32x2 t = (a * f - b * c) * rd;
    s = vsel(par, (f32x2)0.0f, s);
    f32x2 s_cl = vclamp01(s);
    f32x2 t_cl = vclamp01(t);
    i32x2 rec_t = (s_cl != s) | par;
    V3p r_new = r + s_cl * d1;
    f32x2 t_new = vclamp01(dotp(r_new, d2) * re);
    f32x2 t_fin = vsel(rec_t, t_new, t_cl);
    i32x2 rec_s = (t_cl != t) & ~par & (s_cl == s);
    V3p r_new2 = r - t_fin * d2;
    f32x2 s_new = (-dotp(r_new2, d1)) * ra;
    f32x2 s_fin = vsel(rec_s, vclamp01(s_new), s_cl);
    V3p c1 = p1 + s_fin * d1;
    V3p c2 = p2 + t_fin * d2;
    V3p diff = c1 - c2;
    return dotp(diff, diff);
}

__device__ __forceinline__ f32x2 ptri3_min_d2(V3p p0, V3p p1, V3p p2,
                                              V3p v0, V3p v1, V3p v2) {
    V3p e0 = v1 - v0;
    V3p e1 = v2 - v0;
    V3p e2t = v2 - v1;
    f32x2 a  = vmax2(dotp(e0, e0), (f32x2)EPS_PT);
    f32x2 b  = dotp(e0, e1);
    f32x2 c  = vmax2(dotp(e1, e1), (f32x2)EPS_PT);
    f32x2 a2 = vmax2(dotp(e2t, e2t), (f32x2)EPS_PT);
    f32x2 det = vmax2(a * c - b * b, (f32x2)EPS_PT);
    f32x2 ra = vrcp(a), rc = vrcp(c), ra2 = vrcp(a2), rdet = vrcp(det);

    f32x2 best = (f32x2)1e30f;
    V3p pts[3] = {p0, p1, p2};
#pragma unroll
    for (int k = 0; k < 3; ++k) {
        V3p p = pts[k];
        V3p w = p - v0;
        f32x2 d = dotp(e0, w);
        f32x2 e = dotp(e1, w);
        f32x2 f = dotp(w, w);
        f32x2 s = b * e - c * d;
        f32x2 t = b * d - a * e;
        i32x2 in_face = (s >= (f32x2)0.0f) & (t >= (f32x2)0.0f) & ((s + t) <= det);
        f32x2 s01 = vclamp01(d * ra);
        V3p u01 = w - s01 * e0;
        f32x2 d2_e01 = dotp(u01, u01);
        f32x2 t02 = vclamp01(e * rc);
        V3p u02 = w - t02 * e1;
        f32x2 d2_e02 = dotp(u02, u02);
        V3p w2 = p - v1;
        f32x2 dd2 = dotp(e2t, w2);
        f32x2 u12 = vclamp01(dd2 * ra2);
        V3p u12v = w2 - u12 * e2t;
        f32x2 d2_e12 = dotp(u12v, u12v);
        f32x2 d2_face = vmax2((f * det - (d * s + e * t)) * rdet, (f32x2)0.0f);
        f32x2 d2_edge = vmin2(vmin2(d2_e01, d2_e02), d2_e12);
        best = vmin2(best, vsel(in_face, d2_face, d2_edge));
    }
    return best;
}

// Packed body operating on pre-transposed T arrays (component 0 = even pair, 1 = odd pair).
__device__ __forceinline__ f32x2 body_from_T(const f32x2 T1[9], const f32x2 T2[9], f32x2 vmask) {
    V3p A[3]  = { {T1[0], T1[1], T1[2]}, {T1[3], T1[4], T1[5]}, {T1[6], T1[7], T1[8]} };
    V3p Ac[3] = { {T1[0], T1[3], T1[6]}, {T1[1], T1[4], T1[7]}, {T1[2], T1[5], T1[8]} };
    V3p B[3]  = { {T2[0], T2[1], T2[2]}, {T2[3], T2[4], T2[5]}, {T2[6], T2[7], T2[8]} };
    V3p Bc[3] = { {T2[0], T2[3], T2[6]}, {T2[1], T2[4], T2[7]}, {T2[2], T2[5], T2[8]} };

    f32x2 mind2 = (f32x2)1e30f;
    mind2 = vmin2(mind2, ptri3_min_d2(A[0], A[1], A[2], Bc[0], Bc[1], Bc[2]));
    mind2 = vmin2(mind2, ptri3_min_d2(B[0], B[1], B[2], Ac[0], Ac[1], Ac[2]));

    V3p dA[3] = { A[1] - A[0], A[2] - A[1], A[0] - A[2] };
    V3p dB[3] = { B[1] - B[0], B[2] - B[1], B[0] - B[2] };
    f32x2 la[3], lb[3], rla[3], rlb[3];
#pragma unroll
    for (int k = 0; k < 3; ++k) {
        la[k] = dotp(dA[k], dA[k]); rla[k] = vrcp(la[k]);
        lb[k] = dotp(dB[k], dB[k]); rlb[k] = vrcp(lb[k]);
    }
#pragma unroll
    for (int ii = 0; ii < 3; ++ii) {
#pragma unroll
        for (int jj = 0; jj < 3; ++jj) {
            mind2 = vmin2(mind2, edge_edge_d2(A[ii], dA[ii], B[jj], dB[jj],
                                              la[ii], lb[jj], rla[ii], rlb[jj]));
        }
    }
    f32x2 dist;
    dist.x = __builtin_sqrtf(mind2.x);
    dist.y = __builtin_sqrtf(mind2.y);
    return vmax2((f32x2)LOSS_EPS - dist, (f32x2)0.0f) * vmask;
}

// Block reduce + global accumulate; the LAST block to finish also writes the final loss.
__device__ __forceinline__ void block_reduce_atomic_fused(float pen, float val, float* ws,
                                                          float* out, unsigned nwg) {
#pragma unroll
    for (int off = 32; off > 0; off >>= 1) {
        pen += __shfl_down(pen, off);
        val += __shfl_down(val, off);
    }
    __shared__ float sp[4], sv[4];
    int wid = threadIdx.x >> 6;
    if ((threadIdx.x & 63) == 0) { sp[wid] = pen; sv[wid] = val; }
    __syncthreads();
    if (threadIdx.x == 0) {
        atomicAdd(&ws[0], sp[0] + sp[1] + sp[2] + sp[3]);
        atomicAdd(&ws[1], sv[0] + sv[1] + sv[2] + sv[3]);
        __threadfence();                              // publish sums before counter
        unsigned done = atomicAdd((unsigned*)(ws + 2), 1u);
        if (done == nwg - 1) {                        // last block: finalize
            float p = atomicAdd(&ws[0], 0.0f);        // device-scope atomic read
            float v = atomicAdd(&ws[1], 0.0f);
            out[0] = p / fmaxf(v, 1.0f);
        }
    }
}

#define PPT 8                         // pairs per thread (4 packed bodies) — R6-proven
#define PAIRS_PER_BLOCK (256 * PPT)   // 2048

__global__ void __launch_bounds__(256)
pen_loss_pipe2(const float* __restrict__ tris, const int* __restrict__ idx,
               float* __restrict__ ws, float* __restrict__ out,
               int npairs, int F, int P, int nwg) {
    // Bijective XCD chunk swizzle (m204).
    int pb = blockIdx.x;
    int x = pb & 7, j = pb >> 3;
    int q8 = nwg >> 3, r8 = nwg & 7;
    int start = (x < r8) ? x * (q8 + 1) : r8 * (q8 + 1) + (x - r8) * q8;
    int lb = start + j;
    int tid = (int)threadIdx.x;
    int p0 = lb * PAIRS_PER_BLOCK + tid;

    // 1) All idx loads upfront (coalesced, nontemporal: keep L2 for the table).
    //    Offsets are FLOAT indices directly into the original tris rows (9 floats).
    int o1[PPT], o2[PPT];
    float vm[PPT];
#pragma unroll
    for (int k = 0; k < PPT; ++k) {
        int p = p0 + k * 256;
        int pc = min(p, npairs - 1);
        long long pr = __builtin_nontemporal_load((const long long*)idx + pc);
        int rx = (int)(pr & 0xffffffffLL);
        int ry = (int)(pr >> 32);
        vm[k] = (p < npairs && rx >= 0) ? 1.0f : 0.0f;
        int b = (pc >= P) + (pc >= 2 * P) + (pc >= 3 * P);   // pc / P without idiv
        int base = b * F;
        o1[k] = (base + max(rx, 0)) * 9;
        o2[k] = (base + max(ry, 0)) * 9;
    }

    // Staging for one body (2 pairs): per triangle 2x dwordx4 + 1 dword,
    // loaded DIRECTLY from tris (4B-aligned dwordx4 is legal on gfx950).
    // PACKT consumes it; the next LOADBODY refills while the body computes.
    float4 qAe0, qAe1, qBe0, qBe1, qAo0, qAo1, qBo0, qBo1;
    float  sAe, sBe, sAo, sBo;

#define LOADBODY(m) do {                                                      \
        const int ev = 2 * (m), od = 2 * (m) + 1;                             \
        qAe0 = *(const float4*)(tris + o1[ev]);                               \
        qAe1 = *(const float4*)(tris + o1[ev] + 4);                           \
        sAe  = tris[o1[ev] + 8];                                              \
        qBe0 = *(const float4*)(tris + o2[ev]);                               \
        qBe1 = *(const float4*)(tris + o2[ev] + 4);                           \
        sBe  = tris[o2[ev] + 8];                                              \
        qAo0 = *(const float4*)(tris + o1[od]);                               \
        qAo1 = *(const float4*)(tris + o1[od] + 4);                           \
        sAo  = tris[o1[od] + 8];                                              \
        qBo0 = *(const float4*)(tris + o2[od]);                               \
        qBo1 = *(const float4*)(tris + o2[od] + 4);                           \
        sBo  = tris[o2[od] + 8];                                              \
    } while (0)

#define PACKT(T1, T2) do {                                                    \
        T1[0] = (f32x2){qAe0.x, qAo0.x}; T1[1] = (f32x2){qAe0.y, qAo0.y};     \
        T1[2] = (f32x2){qAe0.z, qAo0.z}; T1[3] = (f32x2){qAe0.w, qAo0.w};     \
        T1[4] = (f32x2){qAe1.x, qAo1.x}; T1[5] = (f32x2){qAe1.y, qAo1.y};     \
        T1[6] = (f32x2){qAe1.z, qAo1.z}; T1[7] = (f32x2){qAe1.w, qAo1.w};     \
        T1[8] = (f32x2){sAe, sAo};                                            \
        T2[0] = (f32x2){qBe0.x, qBo0.x}; T2[1] = (f32x2){qBe0.y, qBo0.y};     \
        T2[2] = (f32x2){qBe0.z, qBo0.z}; T2[3] = (f32x2){qBe0.w, qBo0.w};     \
        T2[4] = (f32x2){qBe1.x, qBo1.x}; T2[5] = (f32x2){qBe1.y, qBo1.y};     \
        T2[6] = (f32x2){qBe1.z, qBo1.z}; T2[7] = (f32x2){qBe1.w, qBo1.w};     \
        T2[8] = (f32x2){sBe, sBo};                                            \
    } while (0)

    LOADBODY(0);
    f32x2 pen2 = (f32x2)0.0f;
#pragma unroll
    for (int m = 0; m < PPT / 2; ++m) {
        f32x2 T1[9], T2[9];
        PACKT(T1, T2);                     // consumes staging (waits loads), frees it
        if (m < PPT / 2 - 1) LOADBODY(m + 1);  // next body's gathers fly under the body
        f32x2 vmm = {vm[2 * m], vm[2 * m + 1]};
        pen2 += body_from_T(T1, T2, vmm);
    }
#undef LOADBODY
#undef PACKT

    float pen_s = pen2.x + pen2.y;
    float val_s = 0.0f;
#pragma unroll
    for (int k = 0; k < PPT; ++k) val_s += vm[k];
    block_reduce_atomic_fused(pen_s, val_s, ws, out, (unsigned)nwg);
}

extern "C" void kernel_launch(void* const* d_in, const int* in_sizes, int n_in,
                              void* d_out, int out_size, void* d_ws, size_t ws_size,
                              hipStream_t stream) {
    const float* tris = (const float*)d_in[0];
    const int* idx = (const int*)d_in[1];
    float* out = (float*)d_out;
    float* ws = (float*)d_ws;

    const int B = 4;
    int F = in_sizes[0] / (B * 9);      // 50000
    int npairs = in_sizes[1] / 2;       // 2,000,000
    int P = npairs / B;                 // 500,000

    hipMemsetAsync(d_ws, 0, 12, stream);   // ws[0]=pen, ws[1]=val, ws[2]=block counter
    int nwg = (npairs + PAIRS_PER_BLOCK - 1) / PAIRS_PER_BLOCK;   // 977
    pen_loss_pipe2<<<nwg, 256, 0, stream>>>(tris, idx, ws, out,
                                            npairs, F, P, nwg);
    // finalize fused into the last block of pen_loss_pipe2
}